// Round 1
// baseline (2286.323 us; speedup 1.0000x reference)
//
#include <hip/hip_runtime.h>
#include <math.h>

// Problem constants
#define NB   16
#define NCH  8
#define IMG  256
#define HID  64

#define HT      18          // h tile (16 + 1 halo each side)
#define NPIX    (HT*HT)     // 324
#define HSTRIDE 68          // padded per-pixel channel stride (64 + 4) -> conflict-free neighbor reads
#define OUT_TAIL (NB*NCH*IMG*IMG)   // 8388608, logdet lives after this

__device__ __forceinline__ float sigmoidf_(float x) {
    return 1.0f / (1.0f + expf(-x));
}

__global__ void init_logdet_kernel(const float* __restrict__ logdet,
                                   float* __restrict__ outp) {
    int i = threadIdx.x;
    if (i < NB) outp[OUT_TAIL + i] = logdet[i];
}

// One block = one (batch, 16x16 pixel tile). 512 threads = 8 waves.
// LDS: h_lds[324][68] fp32 (88128B) + wz_lds[9][64][16] (36864B) + in_lds[6][20][20] (9600B) = 134592B
__global__ __launch_bounds__(512, 2)
void fused_kernel(const float* __restrict__ input,
                  const float* __restrict__ ft,
                  const float* __restrict__ w0, const float* __restrict__ b0,
                  const float* __restrict__ w1, const float* __restrict__ b1,
                  const float* __restrict__ w2, const float* __restrict__ b2,
                  const float* __restrict__ w3, const float* __restrict__ b3,
                  const float* __restrict__ w4, const float* __restrict__ b4,
                  const float* __restrict__ wz, const float* __restrict__ bz,
                  const float* __restrict__ logs,
                  float* __restrict__ outp)
{
    extern __shared__ float smem[];
    float* h_lds  = smem;                        // NPIX*HSTRIDE = 22032 floats
    float* wz_lds = smem + NPIX*HSTRIDE;         // 9216 floats, layout [tap][i][o]
    float* in_lds = wz_lds + 9216;               // 2400 floats, layout [c][20][20]
    __shared__ float red[8];

    const int tid  = threadIdx.x;
    const int bx = blockIdx.x, by = blockIdx.y, b = blockIdx.z;
    const int lane = tid & 63, wv = tid >> 6;    // 8 waves

    // ---------------- Phase A: stage input tile + convz weights ----------------
    {
        const int x0 = bx*16 - 2, y0 = by*16 - 2;
        for (int idx = tid; idx < 2400; idx += 512) {
            int c = idx / 400, r = idx % 400;
            int yy = r / 20, xx = r % 20;
            int gy = y0 + yy, gx = x0 + xx;
            float v = 0.0f;
            if ((unsigned)gy < 256u && (unsigned)gx < 256u) {
                v = (c < 4) ? input[((b*NCH + c)*IMG + gy)*IMG + gx]
                            : ft[((b*2 + (c-4))*IMG + gy)*IMG + gx];
            }
            in_lds[idx] = v;
        }
        // wz is OIHW (16,64,3,3): flat g = o*576 + i*9 + tap
        for (int g = tid; g < 9216; g += 512) {
            int o = g / 576, r = g % 576;
            int i = r / 9,  tap = r % 9;
            wz_lds[(tap*64 + i)*16 + o] = wz[g];
        }
    }
    __syncthreads();

    // ---------------- Phase B: conv0 3x3 (6->64) + ReLU -> h_lds ----------------
    // lane = output channel; wave owns pixels p ≡ wv (mod 8)
    {
        float w0r[54];
        #pragma unroll
        for (int j = 0; j < 54; ++j) w0r[j] = w0[lane*54 + j];
        float bias0 = b0[lane];
        for (int p = wv; p < NPIX; p += 8) {
            int py = p / 18, px = p % 18;
            int gy = by*16 - 1 + py, gx = bx*16 - 1 + px;
            float hval = 0.0f;
            if ((unsigned)gy < 256u && (unsigned)gx < 256u) {   // outside image => stays 0 (convz zero-pad)
                float a0 = bias0, a1 = 0.0f, a2 = 0.0f;
                #pragma unroll
                for (int i = 0; i < 6; ++i) {
                    #pragma unroll
                    for (int ky = 0; ky < 3; ++ky) {
                        const float* rowp = &in_lds[i*400 + (py+ky)*20 + px];
                        const float* wp   = &w0r[i*9 + ky*3];
                        a0 = fmaf(rowp[0], wp[0], a0);
                        a1 = fmaf(rowp[1], wp[1], a1);
                        a2 = fmaf(rowp[2], wp[2], a2);
                    }
                }
                hval = fmaxf(a0 + a1 + a2, 0.0f);
            }
            h_lds[p*HSTRIDE + lane] = hval;
        }
    }
    // No barrier needed: phases B and C touch only wave-private pixels.

    // ---------------- Phase C: 4x (1x1 conv 64->64 + ReLU), in-place ----------------
    {
        const float* Wl[4] = {w1, w2, w3, w4};
        const float* Bl[4] = {b1, b2, b3, b4};
        for (int l = 0; l < 4; ++l) {
            float wr[64];
            const float4* wrow = (const float4*)(Wl[l] + lane*64);
            #pragma unroll
            for (int j = 0; j < 16; ++j) {
                float4 t = wrow[j];
                wr[4*j+0] = t.x; wr[4*j+1] = t.y; wr[4*j+2] = t.z; wr[4*j+3] = t.w;
            }
            float bl = Bl[l][lane];
            for (int p = wv; p < NPIX; p += 8) {
                int py = p / 18, px = p % 18;
                int gy = by*16 - 1 + py, gx = bx*16 - 1 + px;
                if ((unsigned)gy >= 256u || (unsigned)gx >= 256u) continue; // keep halo zeros
                const float4* hv = (const float4*)&h_lds[p*HSTRIDE];
                float a0 = bl, a1 = 0.0f, a2 = 0.0f, a3 = 0.0f;
                #pragma unroll
                for (int j = 0; j < 16; ++j) {
                    float4 h4 = hv[j];
                    a0 = fmaf(h4.x, wr[4*j+0], a0);
                    a1 = fmaf(h4.y, wr[4*j+1], a1);
                    a2 = fmaf(h4.z, wr[4*j+2], a2);
                    a3 = fmaf(h4.w, wr[4*j+3], a3);
                }
                float nh = fmaxf((a0+a1)+(a2+a3), 0.0f);
                h_lds[p*HSTRIDE + lane] = nh;   // same-wave in-place: reads precede write (data dep)
            }
        }
    }
    __syncthreads();

    // ---------------- z1 passthrough copy ----------------
    for (int idx = tid; idx < 1024; idx += 512) {
        int c = idx >> 8, q = idx & 255;
        int oy = q >> 4, ox = q & 15;
        outp[((b*NCH + c)*IMG + by*16 + oy)*IMG + bx*16 + ox] =
            in_lds[c*400 + (oy+2)*20 + (ox+2)];
    }

    // ---------------- Phase D: convz 3x3 (64->16) + scale + RQ spline ----------------
    float lad_sum = 0.0f;
    {
        const int o = lane & 15, pg = lane >> 4;   // lane = pg*16 + o
        float accs[8];
        #pragma unroll
        for (int it = 0; it < 8; ++it) accs[it] = 0.0f;

        for (int tap = 0; tap < 9; ++tap) {
            int ky = tap / 3, kx = tap % 3;
            float wr[64];
            #pragma unroll
            for (int i = 0; i < 64; ++i) wr[i] = wz_lds[(tap*64 + i)*16 + o];
            #pragma unroll
            for (int it = 0; it < 8; ++it) {
                int q  = it*32 + wv*4 + pg;        // 0..255; pg => consecutive ox
                int oy = q >> 4, ox = q & 15;
                int hp = (oy + ky)*18 + (ox + kx);
                const float4* hv = (const float4*)&h_lds[hp*HSTRIDE];
                float s0 = 0.0f, s1 = 0.0f, s2 = 0.0f, s3 = 0.0f;
                #pragma unroll
                for (int j = 0; j < 16; ++j) {
                    float4 h4 = hv[j];
                    s0 = fmaf(h4.x, wr[4*j+0], s0);
                    s1 = fmaf(h4.y, wr[4*j+1], s1);
                    s2 = fmaf(h4.z, wr[4*j+2], s2);
                    s3 = fmaf(h4.w, wr[4*j+3], s3);
                }
                accs[it] += (s0+s1)+(s2+s3);
            }
        }

        float scale = expf(3.0f * logs[o]);
        float bzo   = bz[o];
        int co = (lane >> 2) & 3, kk = lane & 3;
        int gbase = lane & ~3;

        #pragma unroll
        for (int it = 0; it < 8; ++it) {
            float v  = (accs[it] + bzo) * scale;
            float pw = __shfl(v, gbase + 0, 64);
            float ph = __shfl(v, gbase + 1, 64);
            float pd = __shfl(v, gbase + 2, 64);
            float ps = __shfl(v, gbase + 3, 64);
            int q  = it*32 + wv*4 + pg;
            int oy = q >> 4, ox = q & 15;
            int gy = by*16 + oy, gx = bx*16 + ox;
            float x = input[((b*NCH + 4 + co)*IMG + gy)*IMG + gx];

            bool inside = (x > -0.5f) && (x < 0.5f);
            float xs = inside ? x : 0.0f;
            float wf = sigmoidf_(pw)*0.998f + 0.001f;   // 1-2*MIN_BW, MIN_BW
            float hh = sigmoidf_(ph)*0.998f + 0.001f;
            float dd = expf(pd)*0.999f + 0.001f;        // 1-MIN_D, MIN_D
            bool bin1 = (xs >= wf - 0.5f);
            float in_cw = bin1 ? (wf - 0.5f) : -0.5f;
            float in_w  = bin1 ? (1.0f - wf) : wf;
            float in_ch = bin1 ? (hh - 0.5f) : -0.5f;
            float in_h  = bin1 ? (1.0f - hh) : hh;
            float delta = in_h / in_w;
            float d0 = bin1 ? dd : 1.0f;
            float d1 = bin1 ? 1.0f : dd;
            float theta = (xs - in_cw) / in_w;
            float t1mt  = theta * (1.0f - theta);
            float denom = delta + (d0 + d1 - 2.0f*delta)*t1mt;
            float th2   = theta * theta;
            float ov    = in_ch + in_h*(delta*th2 + d0*t1mt)/denom;
            float omt   = 1.0f - theta;
            float dnum  = delta*delta*(d1*th2 + 2.0f*delta*t1mt + d0*omt*omt);
            float lad   = logf(dnum) - 2.0f*logf(denom);
            ov = fminf(fmaxf(ov, -0.5f), 0.5f);
            ov = inside ? ov : x;
            lad = inside ? lad : 0.0f;
            float out2 = ov + ps;
            if (kk == 0) {
                outp[((b*NCH + 4 + co)*IMG + gy)*IMG + gx] = out2;
                lad_sum += lad;
            }
        }
    }

    // ---------------- logdet reduction ----------------
    #pragma unroll
    for (int off = 32; off > 0; off >>= 1)
        lad_sum += __shfl_down(lad_sum, off, 64);
    if (lane == 0) red[wv] = lad_sum;
    __syncthreads();
    if (tid == 0) {
        float t = 0.0f;
        #pragma unroll
        for (int i = 0; i < 8; ++i) t += red[i];
        atomicAdd(&outp[OUT_TAIL + b], t);
    }
}

extern "C" void kernel_launch(void* const* d_in, const int* in_sizes, int n_in,
                              void* d_out, int out_size, void* d_ws, size_t ws_size,
                              hipStream_t stream) {
    const float* input  = (const float*)d_in[0];
    const float* logdet = (const float*)d_in[1];
    const float* ft     = (const float*)d_in[2];
    const float* w0 = (const float*)d_in[3];
    const float* b0 = (const float*)d_in[4];
    const float* w1 = (const float*)d_in[5];
    const float* b1 = (const float*)d_in[6];
    const float* w2 = (const float*)d_in[7];
    const float* b2 = (const float*)d_in[8];
    const float* w3 = (const float*)d_in[9];
    const float* b3 = (const float*)d_in[10];
    const float* w4 = (const float*)d_in[11];
    const float* b4 = (const float*)d_in[12];
    const float* wz = (const float*)d_in[13];
    const float* bz = (const float*)d_in[14];
    const float* logs = (const float*)d_in[15];
    float* outp = (float*)d_out;

    size_t smem = (size_t)(NPIX*HSTRIDE + 9216 + 2400) * sizeof(float);  // 134592 B
    hipFuncSetAttribute((const void*)fused_kernel,
                        hipFuncAttributeMaxDynamicSharedMemorySize, (int)smem);

    init_logdet_kernel<<<1, 64, 0, stream>>>(logdet, outp);
    fused_kernel<<<dim3(16, 16, NB), 512, smem, stream>>>(
        input, ft, w0, b0, w1, b1, w2, b2, w3, b3, w4, b4, wz, bz, logs, outp);
}

// Round 2
// 298.557 us; speedup vs baseline: 7.6579x; 7.6579x over previous
//
#include <hip/hip_runtime.h>
#include <math.h>

// Problem constants
#define IMG 256
#define OUT_TAIL (16*8*256*256)   // logdet lives after the output tensor
#define HSTR 72                   // bf16 elems per H row (64 + 8 pad)
#define NSTRIP 21                 // 21 strips of 16 pixels cover 18x18=324 (+12 pad)

typedef __bf16 bf8_t __attribute__((ext_vector_type(8)));
typedef float f4_t __attribute__((ext_vector_type(4)));

__device__ __forceinline__ unsigned int rne16u(float x) {
    unsigned u = __float_as_uint(x);
    return (u + 0x7fffu + ((u >> 16) & 1u)) >> 16;
}
__device__ __forceinline__ unsigned int pack2(float a, float b) {
    return rne16u(a) | (rne16u(b) << 16);
}
__device__ __forceinline__ bf8_t as_bf8(uint4 u) {
    return __builtin_bit_cast(bf8_t, u);
}

// ---------------- prep: split weights into hi/lo bf16 MFMA A-fragments ----------------
// frag ids: conv0: 0..7 (Mt*2+ks) ; layers1-4: 8+(l-1)*8+Mt*2+ks ; convz: 40+tap*2+ks
// record: [frag][lane][hi u32 x4 | lo u32 x4]
__global__ void prep_kernel(const float* __restrict__ w0, const float* __restrict__ w1,
                            const float* __restrict__ w2, const float* __restrict__ w3,
                            const float* __restrict__ w4, const float* __restrict__ wz,
                            unsigned int* __restrict__ ws) {
    int f = blockIdx.x;          // 0..57
    int lane = threadIdx.x;      // 0..63
    int m = lane & 15, qd = lane >> 4;
    float vals[8];
    if (f < 8) {                 // conv0: K = ch*9+tap, 54 real
        int Mt = f >> 1, ks = f & 1;
        int c = Mt * 16 + m;
        for (int j = 0; j < 8; ++j) {
            int k = ks * 32 + qd * 8 + j;
            vals[j] = (k < 54) ? w0[c * 54 + k] : 0.0f;
        }
    } else if (f < 40) {         // 1x1 layers
        int r = f - 8, l = r >> 3, fr = r & 7;
        int Mt = fr >> 1, ks = fr & 1;
        const float* wp = (l == 0) ? w1 : (l == 1) ? w2 : (l == 2) ? w3 : w4;
        int c = Mt * 16 + m;
        for (int j = 0; j < 8; ++j) vals[j] = wp[c * 64 + ks * 32 + qd * 8 + j];
    } else {                     // convz: per-tap
        int r = f - 40, tap = r >> 1, ks = r & 1;
        for (int j = 0; j < 8; ++j) {
            int k = ks * 32 + qd * 8 + j;
            vals[j] = wz[(m * 64 + k) * 9 + tap];
        }
    }
    unsigned int hi[4], lo[4];
    for (int i = 0; i < 4; ++i) {
        float a = vals[2 * i], c = vals[2 * i + 1];
        unsigned ha = rne16u(a), hc = rne16u(c);
        float ra = a - __uint_as_float(ha << 16);
        float rc = c - __uint_as_float(hc << 16);
        hi[i] = ha | (rne16u(c) << 16);
        lo[i] = rne16u(ra) | (rne16u(rc) << 16);
        (void)hc;
    }
    unsigned int* p = ws + (size_t)(f * 64 + lane) * 8;
    for (int i = 0; i < 4; ++i) { p[i] = hi[i]; p[4 + i] = lo[i]; }
}

__global__ void init_logdet_kernel(const float* __restrict__ logdet, float* __restrict__ outp) {
    int i = threadIdx.x;
    if (i < 16) outp[OUT_TAIL + i] = logdet[i];
}

// ---------------- fused main kernel ----------------
// One block = one (batch, 16x16 tile). 256 threads = 4 waves.
// LDS: Hs[336][72] bf16 (48384 B) + in_s[2528] bf16 (5056 B) + red (16 B) ~= 53.4 KB -> 3 blocks/CU
__global__ __launch_bounds__(256, 3)
void fused_kernel(const float* __restrict__ input, const float* __restrict__ ft,
                  const float* __restrict__ b0, const float* __restrict__ b1,
                  const float* __restrict__ b2, const float* __restrict__ b3,
                  const float* __restrict__ b4, const float* __restrict__ bz,
                  const float* __restrict__ logs, const unsigned int* __restrict__ wsp,
                  float* __restrict__ outp)
{
    __shared__ unsigned short Hs[336 * HSTR];
    __shared__ unsigned short in_s[2528];     // [6][21][20] + zero sentinel @2520
    __shared__ float red[4];

    const int tid = threadIdx.x;
    const int bx = blockIdx.x, by = blockIdx.y, b = blockIdx.z;
    const int lane = tid & 63, w = tid >> 6;
    const int m = lane & 15, q = lane >> 4;
    const uint4* W4 = (const uint4*)wsp;

    // ---------------- stage input tile (bf16) + z1 passthrough ----------------
    {
        const int x0 = bx * 16 - 2, y0 = by * 16 - 2;
        for (int idx = tid; idx < 2400; idx += 256) {
            int c = idx / 400, r = idx - c * 400;
            int yy = r / 20, xx = r - yy * 20;
            int gy = y0 + yy, gx = x0 + xx;
            float v = 0.0f;
            if ((unsigned)gy < 256u && (unsigned)gx < 256u)
                v = (c < 4) ? input[((size_t)(b * 8 + c) * 256 + gy) * 256 + gx]
                            : ft[((size_t)(b * 2 + (c - 4)) * 256 + gy) * 256 + gx];
            in_s[c * 420 + yy * 20 + xx] = (unsigned short)rne16u(v);
        }
        if (tid == 0) in_s[2520] = 0;
        // z1 exact fp32 passthrough: 1024 floats, 4 per thread
        int c = tid >> 6;
        int rem = (tid & 63) * 4;
        int oy = rem >> 4, ox = rem & 15;
        size_t o = ((size_t)(b * 8 + c) * 256 + by * 16 + oy) * 256 + bx * 16 + ox;
        *(float4*)&outp[o] = *(const float4*)&input[o];
    }
    __syncthreads();

    // ---------------- conv0 3x3 (6->64) via MFMA, im2col gather from in_s ----------------
    {
        int koff[16]; unsigned vmask = 0;
        #pragma unroll
        for (int ks = 0; ks < 2; ++ks)
            #pragma unroll
            for (int j = 0; j < 8; ++j) {
                int k = ks * 32 + q * 8 + j;
                int ch = k / 9, tap = k - ch * 9;
                int kky = tap / 3, kkx = tap - kky * 3;
                int idx = ks * 8 + j;
                koff[idx] = ch * 420 + kky * 20 + kkx;
                if (k < 54) vmask |= (1u << idx);
            }
        uint4 Ah[4][2], Al[4][2];
        #pragma unroll
        for (int Mt = 0; Mt < 4; ++Mt)
            #pragma unroll
            for (int ks = 0; ks < 2; ++ks) {
                const uint4* p = W4 + ((size_t)(Mt * 2 + ks) * 64 + lane) * 2;
                Ah[Mt][ks] = p[0]; Al[Mt][ks] = p[1];
            }
        float bv[16];
        #pragma unroll
        for (int Mt = 0; Mt < 4; ++Mt)
            #pragma unroll
            for (int r = 0; r < 4; ++r) bv[Mt * 4 + r] = b0[Mt * 16 + q * 4 + r];

        #pragma unroll 1
        for (int s = w; s < NSTRIP; s += 4) {
            int pix = 16 * s + m;
            int py = pix / 18, px = pix - py * 18;
            int base = py * 20 + px;
            uint4 B[2];
            #pragma unroll
            for (int ks = 0; ks < 2; ++ks) {
                unsigned e[8];
                #pragma unroll
                for (int j = 0; j < 8; ++j) {
                    int idx = ks * 8 + j;
                    int a = ((vmask >> idx) & 1u) ? (base + koff[idx]) : 2520;
                    e[j] = in_s[a];
                }
                B[ks] = make_uint4(e[0] | (e[1] << 16), e[2] | (e[3] << 16),
                                   e[4] | (e[5] << 16), e[6] | (e[7] << 16));
            }
            unsigned short* hrow = Hs + pix * HSTR;
            #pragma unroll
            for (int Mt = 0; Mt < 4; ++Mt) {
                f4_t a;
                #pragma unroll
                for (int r = 0; r < 4; ++r) a[r] = bv[Mt * 4 + r];
                #pragma unroll
                for (int ks = 0; ks < 2; ++ks) {
                    a = __builtin_amdgcn_mfma_f32_16x16x32_bf16(as_bf8(Ah[Mt][ks]), as_bf8(B[ks]), a, 0, 0, 0);
                    a = __builtin_amdgcn_mfma_f32_16x16x32_bf16(as_bf8(Al[Mt][ks]), as_bf8(B[ks]), a, 0, 0, 0);
                }
                uint2 pr;
                pr.x = pack2(fmaxf(a[0], 0.f), fmaxf(a[1], 0.f));
                pr.y = pack2(fmaxf(a[2], 0.f), fmaxf(a[3], 0.f));
                *(uint2*)(hrow + Mt * 16 + q * 4) = pr;
            }
        }
    }

    // ---------------- 4x (1x1 conv 64->64 + ReLU) via MFMA, in-place H, no barriers ----------------
    #pragma unroll 1
    for (int l = 1; l <= 4; ++l) {
        const float* bl = (l == 1) ? b1 : (l == 2) ? b2 : (l == 3) ? b3 : b4;
        uint4 Ah[4][2], Al[4][2];
        #pragma unroll
        for (int Mt = 0; Mt < 4; ++Mt)
            #pragma unroll
            for (int ks = 0; ks < 2; ++ks) {
                const uint4* p = W4 + ((size_t)((8 + (l - 1) * 8) + Mt * 2 + ks) * 64 + lane) * 2;
                Ah[Mt][ks] = p[0]; Al[Mt][ks] = p[1];
            }
        float bv[16];
        #pragma unroll
        for (int Mt = 0; Mt < 4; ++Mt)
            #pragma unroll
            for (int r = 0; r < 4; ++r) bv[Mt * 4 + r] = bl[Mt * 16 + q * 4 + r];

        #pragma unroll 1
        for (int s = w; s < NSTRIP; s += 4) {
            int pix = 16 * s + m;
            const uint4* hp = (const uint4*)(Hs + pix * HSTR);
            uint4 B0 = hp[q], B1 = hp[4 + q];   // k = ks*32 + q*8 .. +7
            f4_t acc[4];
            #pragma unroll
            for (int Mt = 0; Mt < 4; ++Mt) {
                f4_t a;
                #pragma unroll
                for (int r = 0; r < 4; ++r) a[r] = bv[Mt * 4 + r];
                a = __builtin_amdgcn_mfma_f32_16x16x32_bf16(as_bf8(Ah[Mt][0]), as_bf8(B0), a, 0, 0, 0);
                a = __builtin_amdgcn_mfma_f32_16x16x32_bf16(as_bf8(Al[Mt][0]), as_bf8(B0), a, 0, 0, 0);
                a = __builtin_amdgcn_mfma_f32_16x16x32_bf16(as_bf8(Ah[Mt][1]), as_bf8(B1), a, 0, 0, 0);
                a = __builtin_amdgcn_mfma_f32_16x16x32_bf16(as_bf8(Al[Mt][1]), as_bf8(B1), a, 0, 0, 0);
                acc[Mt] = a;
            }
            float msk = 1.0f;
            if (l == 4) {   // zero h outside the image (convz zero-pad semantics)
                int py = pix / 18, px = pix - py * 18;
                int gy = by * 16 - 1 + py, gx = bx * 16 - 1 + px;
                msk = ((unsigned)gy < 256u && (unsigned)gx < 256u) ? 1.0f : 0.0f;
            }
            unsigned short* hrow = Hs + pix * HSTR;
            #pragma unroll
            for (int Mt = 0; Mt < 4; ++Mt) {
                uint2 pr;
                pr.x = pack2(fmaxf(acc[Mt][0], 0.f) * msk, fmaxf(acc[Mt][1], 0.f) * msk);
                pr.y = pack2(fmaxf(acc[Mt][2], 0.f) * msk, fmaxf(acc[Mt][3], 0.f) * msk);
                *(uint2*)(hrow + Mt * 16 + q * 4) = pr;
            }
        }
    }
    __syncthreads();

    // ---------------- convz 3x3 (64->16) via MFMA + RQ spline (shuffle-free epilogue) ----------------
    {
        float bzv[4], scl[4];
        #pragma unroll
        for (int r = 0; r < 4; ++r) {
            int c = q * 4 + r;
            bzv[r] = bz[c];
            scl[r] = expf(3.0f * logs[c]);
        }
        f4_t acc[4];
        #pragma unroll
        for (int rr = 0; rr < 4; ++rr) { acc[rr][0] = 0.f; acc[rr][1] = 0.f; acc[rr][2] = 0.f; acc[rr][3] = 0.f; }
        const int oy0 = w * 4;
        #pragma unroll 1
        for (int tap = 0; tap < 9; ++tap) {
            int ky = tap / 3, kx = tap - ky * 3;
            #pragma unroll
            for (int ks = 0; ks < 2; ++ks) {
                const uint4* p = W4 + ((size_t)(40 + tap * 2 + ks) * 64 + lane) * 2;
                uint4 ah = p[0], al = p[1];
                #pragma unroll
                for (int rr = 0; rr < 4; ++rr) {
                    int nbr = (oy0 + rr + ky) * 18 + (m + kx);
                    uint4 Bv = *(const uint4*)(Hs + nbr * HSTR + ks * 32 + q * 8);
                    acc[rr] = __builtin_amdgcn_mfma_f32_16x16x32_bf16(as_bf8(ah), as_bf8(Bv), acc[rr], 0, 0, 0);
                    acc[rr] = __builtin_amdgcn_mfma_f32_16x16x32_bf16(as_bf8(al), as_bf8(Bv), acc[rr], 0, 0, 0);
                }
            }
        }
        // spline: lane(q,m) holds params w,h,d,shift for channel co=q at pixel (oy, ox=m) in regs 0..3
        float lad_sum = 0.0f;
        #pragma unroll 1
        for (int rr = 0; rr < 4; ++rr) {
            int gy = by * 16 + oy0 + rr, gx = bx * 16 + m;
            size_t xi = ((size_t)(b * 8 + 4 + q) * 256 + gy) * 256 + gx;
            float x = input[xi];
            float pw = (acc[rr][0] + bzv[0]) * scl[0];
            float ph = (acc[rr][1] + bzv[1]) * scl[1];
            float pd = (acc[rr][2] + bzv[2]) * scl[2];
            float ps = (acc[rr][3] + bzv[3]) * scl[3];

            bool inside = (x > -0.5f) && (x < 0.5f);
            float xs = inside ? x : 0.0f;
            float wf = 1.0f / (1.0f + expf(-pw)) * 0.998f + 0.001f;
            float hh = 1.0f / (1.0f + expf(-ph)) * 0.998f + 0.001f;
            float dd = expf(pd) * 0.999f + 0.001f;
            bool bin1 = (xs >= wf - 0.5f);
            float in_cw = bin1 ? (wf - 0.5f) : -0.5f;
            float in_w  = bin1 ? (1.0f - wf) : wf;
            float in_ch = bin1 ? (hh - 0.5f) : -0.5f;
            float in_h  = bin1 ? (1.0f - hh) : hh;
            float delta = in_h / in_w;
            float d0 = bin1 ? dd : 1.0f;
            float d1 = bin1 ? 1.0f : dd;
            float theta = (xs - in_cw) / in_w;
            float t1mt  = theta * (1.0f - theta);
            float denom = delta + (d0 + d1 - 2.0f * delta) * t1mt;
            float th2   = theta * theta;
            float ov    = in_ch + in_h * (delta * th2 + d0 * t1mt) / denom;
            float omt   = 1.0f - theta;
            float dnum  = delta * delta * (d1 * th2 + 2.0f * delta * t1mt + d0 * omt * omt);
            float lad   = logf(dnum) - 2.0f * logf(denom);
            ov  = fminf(fmaxf(ov, -0.5f), 0.5f);
            ov  = inside ? ov : x;
            lad = inside ? lad : 0.0f;
            outp[xi] = ov + ps;
            lad_sum += lad;
        }
        #pragma unroll
        for (int off = 32; off > 0; off >>= 1)
            lad_sum += __shfl_down(lad_sum, off, 64);
        if (lane == 0) red[w] = lad_sum;
    }
    __syncthreads();
    if (tid == 0)
        atomicAdd(&outp[OUT_TAIL + b], red[0] + red[1] + red[2] + red[3]);
}

extern "C" void kernel_launch(void* const* d_in, const int* in_sizes, int n_in,
                              void* d_out, int out_size, void* d_ws, size_t ws_size,
                              hipStream_t stream) {
    const float* input  = (const float*)d_in[0];
    const float* logdet = (const float*)d_in[1];
    const float* ft     = (const float*)d_in[2];
    const float* w0 = (const float*)d_in[3];
    const float* b0 = (const float*)d_in[4];
    const float* w1 = (const float*)d_in[5];
    const float* b1 = (const float*)d_in[6];
    const float* w2 = (const float*)d_in[7];
    const float* b2 = (const float*)d_in[8];
    const float* w3 = (const float*)d_in[9];
    const float* b3 = (const float*)d_in[10];
    const float* w4 = (const float*)d_in[11];
    const float* b4 = (const float*)d_in[12];
    const float* wz = (const float*)d_in[13];
    const float* bz = (const float*)d_in[14];
    const float* logs = (const float*)d_in[15];
    float* outp = (float*)d_out;
    unsigned int* wsp = (unsigned int*)d_ws;

    prep_kernel<<<58, 64, 0, stream>>>(w0, w1, w2, w3, w4, wz, wsp);
    init_logdet_kernel<<<1, 64, 0, stream>>>(logdet, outp);
    fused_kernel<<<dim3(16, 16, 16), 256, 0, stream>>>(
        input, ft, b0, b1, b2, b3, b4, bz, logs, wsp, outp);
}

// Round 3
// 270.287 us; speedup vs baseline: 8.4589x; 1.1046x over previous
//
#include <hip/hip_runtime.h>
#include <math.h>

// Problem constants
#define OUT_TAIL (16*8*256*256)   // logdet lives after the output tensor
#define HSTR   68                 // bf16 elems per H row (64 + 4 pad) -> odd dword-pair stride, b64 conflict-free
#define HROWB  136                // bytes per H row
#define SSTRIDE 2176              // 16 rows * HROWB = strip stride in bytes
#define INSTR  408                // in_s per-channel stride (shorts)

typedef __bf16 bf8_t __attribute__((ext_vector_type(8)));
typedef float  f4_t  __attribute__((ext_vector_type(4)));

__device__ __forceinline__ unsigned rne16u_(float x) {
    unsigned u = __float_as_uint(x);
    return (u + 0x7fffu + ((u >> 16) & 1u)) >> 16;
}
#if __has_builtin(__builtin_amdgcn_cvt_pk_bf16_f32)
__device__ __forceinline__ unsigned pack2f(float a, float b) {
    typedef __bf16 bf2_t __attribute__((ext_vector_type(2)));
    bf2_t r = __builtin_amdgcn_cvt_pk_bf16_f32(a, b);
    return __builtin_bit_cast(unsigned, r);
}
#else
__device__ __forceinline__ unsigned pack2f(float a, float b) {
    return rne16u_(a) | (rne16u_(b) << 16);
}
#endif
__device__ __forceinline__ bf8_t as_bf8(uint4 u) { return __builtin_bit_cast(bf8_t, u); }

// ---------------- prep: split weights into hi/lo bf16 MFMA A-fragments ----------------
// frag ids: conv0: 0..7 (Mt*2+ks) ; layers1-4: 8+l*8+Mt*2+ks ; convz: 40+tap*2+ks
// record: [frag][lane][hi u32 x4 | lo u32 x4]
__global__ void prep_kernel(const float* __restrict__ w0, const float* __restrict__ w1,
                            const float* __restrict__ w2, const float* __restrict__ w3,
                            const float* __restrict__ w4, const float* __restrict__ wz,
                            unsigned int* __restrict__ ws) {
    int f = blockIdx.x;          // 0..57
    int lane = threadIdx.x;      // 0..63
    int m = lane & 15, qd = lane >> 4;
    float vals[8];
    if (f < 8) {                 // conv0: K = ch*9+tap, 54 real
        int Mt = f >> 1, ks = f & 1;
        int c = Mt * 16 + m;
        for (int j = 0; j < 8; ++j) {
            int k = ks * 32 + qd * 8 + j;
            vals[j] = (k < 54) ? w0[c * 54 + k] : 0.0f;
        }
    } else if (f < 40) {         // 1x1 layers
        int r = f - 8, l = r >> 3, fr = r & 7;
        int Mt = fr >> 1, ks = fr & 1;
        const float* wp = (l == 0) ? w1 : (l == 1) ? w2 : (l == 2) ? w3 : w4;
        int c = Mt * 16 + m;
        for (int j = 0; j < 8; ++j) vals[j] = wp[c * 64 + ks * 32 + qd * 8 + j];
    } else {                     // convz: per-tap
        int r = f - 40, tap = r >> 1, ks = r & 1;
        for (int j = 0; j < 8; ++j) {
            int k = ks * 32 + qd * 8 + j;
            vals[j] = wz[(m * 64 + k) * 9 + tap];
        }
    }
    unsigned int hi[4], lo[4];
    for (int i = 0; i < 4; ++i) {
        float a = vals[2 * i], c = vals[2 * i + 1];
        unsigned ha = rne16u_(a), hc = rne16u_(c);
        float ra = a - __uint_as_float(ha << 16);
        float rc = c - __uint_as_float(hc << 16);
        hi[i] = ha | (hc << 16);
        lo[i] = rne16u_(ra) | (rne16u_(rc) << 16);
    }
    unsigned int* p = ws + (size_t)(f * 64 + lane) * 8;
    for (int i = 0; i < 4; ++i) { p[i] = hi[i]; p[4 + i] = lo[i]; }
}

__global__ void init_logdet_kernel(const float* __restrict__ logdet, float* __restrict__ outp) {
    int i = threadIdx.x;
    if (i < 16) outp[OUT_TAIL + i] = logdet[i];
}

// ---------------- fused main kernel ----------------
// One block = one (batch, 16x16 tile). 256 threads = 4 waves.
// Wave w owns contiguous pixel strips: w0 pixels 0..95 (6 strips), w1 96..175, w2 176..255, w3 256..335.
// LDS: Hs[336][68] bf16 (45696 B) + in_s[2464] bf16 (4928 B) + red -> ~50.6 KB -> 3 blocks/CU
__global__ __launch_bounds__(256, 3)
void fused_kernel(const float* __restrict__ input, const float* __restrict__ ft,
                  const float* __restrict__ b0, const float* __restrict__ b1,
                  const float* __restrict__ b2, const float* __restrict__ b3,
                  const float* __restrict__ b4, const float* __restrict__ bz,
                  const float* __restrict__ logs, const unsigned int* __restrict__ wsp,
                  float* __restrict__ outp)
{
    __shared__ __align__(16) unsigned short Hs[336 * HSTR];
    __shared__ __align__(16) unsigned short in_s[2464];
    __shared__ float red[4];

    const int tid = threadIdx.x;
    const int bx = blockIdx.x, by = blockIdx.y, b = blockIdx.z;
    const int lane = tid & 63;
    const int ws_ = __builtin_amdgcn_readfirstlane(tid >> 6);   // wave id, scalar
    const int m = lane & 15, q = lane >> 4;
    const uint4* W4 = (const uint4*)wsp;
    const bool border = (bx == 0) | (bx == 15) | (by == 0) | (by == 15);

    // ---------------- stage input tile (bf16) + z1 fp32 passthrough ----------------
    {
        const int x0 = bx * 16 - 2, y0 = by * 16 - 2;
        int yy1 = tid / 20, xx1 = tid - yy1 * 20;
        int t2 = tid + 256;
        int yy2 = t2 / 20, xx2 = t2 - yy2 * 20;
        int gy1 = y0 + yy1, gx1 = x0 + xx1;
        int gy2 = y0 + yy2, gx2 = x0 + xx2;
        bool ok1 = ((unsigned)gy1 < 256u) && ((unsigned)gx1 < 256u);
        bool ok2 = ((unsigned)gy2 < 256u) && ((unsigned)gx2 < 256u);
        #pragma unroll
        for (int c = 0; c < 6; ++c) {
            const float* src = (c < 4) ? input + (size_t)(b * 8 + c) * 65536
                                       : ft + (size_t)(b * 2 + (c - 4)) * 65536;
            float v1 = ok1 ? src[gy1 * 256 + gx1] : 0.0f;
            in_s[c * INSTR + yy1 * 20 + xx1] = (unsigned short)(pack2f(v1, 0.0f) & 0xffffu);
            if (tid < 144) {
                float v2 = ok2 ? src[gy2 * 256 + gx2] : 0.0f;
                in_s[c * INSTR + yy2 * 20 + xx2] = (unsigned short)(pack2f(v2, 0.0f) & 0xffffu);
            }
        }
        // z1 exact fp32 passthrough: 4 floats per thread
        int c = tid >> 6;
        int rem = (tid & 63) * 4;
        int oy = rem >> 4, ox = rem & 15;
        size_t o = ((size_t)(b * 8 + c) * 256 + by * 16 + oy) * 256 + bx * 16 + ox;
        *(float4*)&outp[o] = *(const float4*)&input[o];
    }
    __syncthreads();

    const int nstrip = (ws_ == 0) ? 6 : 5;
    const int pbase  = (ws_ == 0) ? 0 : (80 * ws_ + 16);
    const int pix0   = pbase + m;
    const int A0 = pix0 * HROWB + q * 16;   // H B-read base (bytes)
    const int W0 = pix0 * HROWB + q * 8;    // H write base (bytes); + s*SSTRIDE + Mt*32

    // ---------------- conv0 3x3 (6->64) via MFMA, im2col gather from in_s ----------------
    {
        int koffB[16];                      // byte offsets into in_s, per-lane (q-dependent)
        #pragma unroll
        for (int ks = 0; ks < 2; ++ks)
            #pragma unroll
            for (int j = 0; j < 8; ++j) {
                int k = ks * 32 + q * 8 + j;
                int ch = k / 9, tap = k - ch * 9;
                int ky = tap / 3, kx = tap - ky * 3;
                koffB[ks * 8 + j] = (k < 54) ? (ch * INSTR + ky * 20 + kx) * 2 : 0;
            }
        uint4 Ah[8], Al[8];
        #pragma unroll
        for (int f = 0; f < 8; ++f) {
            const uint4* p = W4 + ((size_t)(f * 64) + lane) * 2;
            Ah[f] = p[0]; Al[f] = p[1];
        }
        float bv[16];
        #pragma unroll
        for (int Mt = 0; Mt < 4; ++Mt)
            #pragma unroll
            for (int r = 0; r < 4; ++r) bv[Mt * 4 + r] = b0[Mt * 16 + q * 4 + r];

        int cpy = (pix0 * 1821) >> 15;      // pix0 / 18 (exact for 0..335)
        int cpx = pix0 - cpy * 18;
        #pragma unroll
        for (int s = 0; s < 6; ++s) {
            if (s < nstrip) {
                int ib = (cpy * 20 + cpx) * 2;
                unsigned e[16];
                #pragma unroll
                for (int i = 0; i < 16; ++i)
                    e[i] = *(const unsigned short*)((const char*)in_s + ib + koffB[i]);
                uint4 B0 = make_uint4(e[0] | (e[1] << 16), e[2] | (e[3] << 16),
                                      e[4] | (e[5] << 16), e[6] | (e[7] << 16));
                uint4 B1 = make_uint4(e[8] | (e[9] << 16), e[10] | (e[11] << 16),
                                      e[12] | (e[13] << 16), e[14] | (e[15] << 16));
                #pragma unroll
                for (int Mt = 0; Mt < 4; ++Mt) {
                    f4_t a;
                    #pragma unroll
                    for (int r = 0; r < 4; ++r) a[r] = bv[Mt * 4 + r];
                    a = __builtin_amdgcn_mfma_f32_16x16x32_bf16(as_bf8(Ah[Mt*2+0]), as_bf8(B0), a, 0, 0, 0);
                    a = __builtin_amdgcn_mfma_f32_16x16x32_bf16(as_bf8(Al[Mt*2+0]), as_bf8(B0), a, 0, 0, 0);
                    a = __builtin_amdgcn_mfma_f32_16x16x32_bf16(as_bf8(Ah[Mt*2+1]), as_bf8(B1), a, 0, 0, 0);
                    a = __builtin_amdgcn_mfma_f32_16x16x32_bf16(as_bf8(Al[Mt*2+1]), as_bf8(B1), a, 0, 0, 0);
                    uint2 pr;
                    pr.x = pack2f(fmaxf(a[0], 0.f), fmaxf(a[1], 0.f));
                    pr.y = pack2f(fmaxf(a[2], 0.f), fmaxf(a[3], 0.f));
                    *(uint2*)((char*)Hs + W0 + s * SSTRIDE + Mt * 32) = pr;
                }
            }
            cpx += 16;
            if (cpx >= 18) { cpx -= 18; cpy += 1; }
        }
    }

    // ---------------- 4x (1x1 conv 64->64 + ReLU) via MFMA, in-place H, no barriers ----------------
    #pragma unroll 1
    for (int l = 0; l < 4; ++l) {
        const float* bl = (l == 0) ? b1 : (l == 1) ? b2 : (l == 2) ? b3 : b4;
        uint4 Ah[8], Al[8];
        #pragma unroll
        for (int f = 0; f < 8; ++f) {
            const uint4* p = W4 + ((size_t)((8 + l * 8 + f) * 64) + lane) * 2;
            Ah[f] = p[0]; Al[f] = p[1];
        }
        float bv[16];
        #pragma unroll
        for (int Mt = 0; Mt < 4; ++Mt)
            #pragma unroll
            for (int r = 0; r < 4; ++r) bv[Mt * 4 + r] = bl[Mt * 16 + q * 4 + r];

        #pragma unroll
        for (int s = 0; s < 6; ++s) {
            if (s < nstrip) {
                const char* rp = (const char*)Hs + A0 + s * SSTRIDE;
                uint2 a0 = *(const uint2*)(rp);
                uint2 a1 = *(const uint2*)(rp + 8);
                uint2 a2 = *(const uint2*)(rp + 64);
                uint2 a3 = *(const uint2*)(rp + 72);
                uint4 B0 = make_uint4(a0.x, a0.y, a1.x, a1.y);
                uint4 B1 = make_uint4(a2.x, a2.y, a3.x, a3.y);
                #pragma unroll
                for (int Mt = 0; Mt < 4; ++Mt) {
                    f4_t a;
                    #pragma unroll
                    for (int r = 0; r < 4; ++r) a[r] = bv[Mt * 4 + r];
                    a = __builtin_amdgcn_mfma_f32_16x16x32_bf16(as_bf8(Ah[Mt*2+0]), as_bf8(B0), a, 0, 0, 0);
                    a = __builtin_amdgcn_mfma_f32_16x16x32_bf16(as_bf8(Al[Mt*2+0]), as_bf8(B0), a, 0, 0, 0);
                    a = __builtin_amdgcn_mfma_f32_16x16x32_bf16(as_bf8(Ah[Mt*2+1]), as_bf8(B1), a, 0, 0, 0);
                    a = __builtin_amdgcn_mfma_f32_16x16x32_bf16(as_bf8(Al[Mt*2+1]), as_bf8(B1), a, 0, 0, 0);
                    uint2 pr;
                    pr.x = pack2f(fmaxf(a[0], 0.f), fmaxf(a[1], 0.f));
                    pr.y = pack2f(fmaxf(a[2], 0.f), fmaxf(a[3], 0.f));
                    *(uint2*)((char*)Hs + W0 + s * SSTRIDE + Mt * 32) = pr;
                }
            }
        }
    }

    // ---------------- border blocks: zero H rows outside the image (convz zero-pad) ----------------
    if (border) {
        #pragma unroll
        for (int s = 0; s < 6; ++s) {
            if (s < nstrip) {
                int pixs = pix0 + 16 * s;
                int pys = (pixs * 1821) >> 15;
                int pxs = pixs - pys * 18;
                int gy = by * 16 - 1 + pys, gx = bx * 16 - 1 + pxs;
                if (!(((unsigned)gy < 256u) && ((unsigned)gx < 256u))) {
                    char* zp = (char*)Hs + A0 + s * SSTRIDE;   // q-chunks cover all 64 ch
                    *(uint2*)(zp)      = make_uint2(0, 0);
                    *(uint2*)(zp + 8)  = make_uint2(0, 0);
                    *(uint2*)(zp + 64) = make_uint2(0, 0);
                    *(uint2*)(zp + 72) = make_uint2(0, 0);
                }
            }
        }
    }
    __syncthreads();

    // ---------------- convz 3x3 (64->16) via MFMA + RQ spline (shuffle-free epilogue) ----------------
    {
        // prefetch spline inputs x (z2 channels) and per-channel constants
        float xv[4];
        #pragma unroll
        for (int rr = 0; rr < 4; ++rr) {
            int gy = by * 16 + ws_ * 4 + rr;
            xv[rr] = input[((size_t)(b * 8 + 4 + q) * 256 + gy) * 256 + bx * 16 + m];
        }
        float bzv[4], scl[4];
        #pragma unroll
        for (int r = 0; r < 4; ++r) {
            int c = q * 4 + r;
            bzv[r] = bz[c];
            scl[r] = expf(3.0f * logs[c]);
        }
        f4_t acc[4];
        #pragma unroll
        for (int rr = 0; rr < 4; ++rr) { acc[rr][0]=0.f; acc[rr][1]=0.f; acc[rr][2]=0.f; acc[rr][3]=0.f; }
        const int Z0 = (ws_ * 72 + m) * HROWB + q * 16;
        #pragma unroll
        for (int tap = 0; tap < 9; ++tap) {
            const int ky = tap / 3, kx = tap - ky * 3;
            #pragma unroll
            for (int ks = 0; ks < 2; ++ks) {
                const uint4* p = W4 + ((size_t)((40 + tap * 2 + ks) * 64) + lane) * 2;
                uint4 ah = p[0], al = p[1];
                #pragma unroll
                for (int rr = 0; rr < 4; ++rr) {
                    const char* zp = (const char*)Hs + Z0 + ((rr + ky) * 18 + kx) * HROWB + ks * 64;
                    uint2 u0 = *(const uint2*)zp;
                    uint2 u1 = *(const uint2*)(zp + 8);
                    uint4 Bv = make_uint4(u0.x, u0.y, u1.x, u1.y);
                    acc[rr] = __builtin_amdgcn_mfma_f32_16x16x32_bf16(as_bf8(ah), as_bf8(Bv), acc[rr], 0, 0, 0);
                    acc[rr] = __builtin_amdgcn_mfma_f32_16x16x32_bf16(as_bf8(al), as_bf8(Bv), acc[rr], 0, 0, 0);
                }
            }
        }
        // spline: lane(m,q) holds params w,h,d,shift for channel co=q at pixel (oy, ox=m) in regs 0..3
        float lad_sum = 0.0f;
        #pragma unroll
        for (int rr = 0; rr < 4; ++rr) {
            int gy = by * 16 + ws_ * 4 + rr, gx = bx * 16 + m;
            size_t xi = ((size_t)(b * 8 + 4 + q) * 256 + gy) * 256 + gx;
            float x = xv[rr];
            float pw = (acc[rr][0] + bzv[0]) * scl[0];
            float ph = (acc[rr][1] + bzv[1]) * scl[1];
            float pd = (acc[rr][2] + bzv[2]) * scl[2];
            float ps = (acc[rr][3] + bzv[3]) * scl[3];

            bool inside = (x > -0.5f) && (x < 0.5f);
            float xs = inside ? x : 0.0f;
            float wf = 1.0f / (1.0f + expf(-pw)) * 0.998f + 0.001f;
            float hh = 1.0f / (1.0f + expf(-ph)) * 0.998f + 0.001f;
            float dd = expf(pd) * 0.999f + 0.001f;
            bool bin1 = (xs >= wf - 0.5f);
            float in_cw = bin1 ? (wf - 0.5f) : -0.5f;
            float in_w  = bin1 ? (1.0f - wf) : wf;
            float in_ch = bin1 ? (hh - 0.5f) : -0.5f;
            float in_h  = bin1 ? (1.0f - hh) : hh;
            float delta = in_h / in_w;
            float d0 = bin1 ? dd : 1.0f;
            float d1 = bin1 ? 1.0f : dd;
            float theta = (xs - in_cw) / in_w;
            float t1mt  = theta * (1.0f - theta);
            float denom = delta + (d0 + d1 - 2.0f * delta) * t1mt;
            float th2   = theta * theta;
            float ov    = in_ch + in_h * (delta * th2 + d0 * t1mt) / denom;
            float omt   = 1.0f - theta;
            float dnum  = delta * delta * (d1 * th2 + 2.0f * delta * t1mt + d0 * omt * omt);
            float lad   = logf(dnum) - 2.0f * logf(denom);
            ov  = fminf(fmaxf(ov, -0.5f), 0.5f);
            ov  = inside ? ov : x;
            lad = inside ? lad : 0.0f;
            outp[xi] = ov + ps;
            lad_sum += lad;
        }
        #pragma unroll
        for (int off = 32; off > 0; off >>= 1)
            lad_sum += __shfl_down(lad_sum, off, 64);
        if (lane == 0) red[ws_] = lad_sum;
    }
    __syncthreads();
    if (tid == 0)
        atomicAdd(&outp[OUT_TAIL + b], red[0] + red[1] + red[2] + red[3]);
}

extern "C" void kernel_launch(void* const* d_in, const int* in_sizes, int n_in,
                              void* d_out, int out_size, void* d_ws, size_t ws_size,
                              hipStream_t stream) {
    const float* input  = (const float*)d_in[0];
    const float* logdet = (const float*)d_in[1];
    const float* ft     = (const float*)d_in[2];
    const float* w0 = (const float*)d_in[3];
    const float* b0 = (const float*)d_in[4];
    const float* w1 = (const float*)d_in[5];
    const float* b1 = (const float*)d_in[6];
    const float* w2 = (const float*)d_in[7];
    const float* b2 = (const float*)d_in[8];
    const float* w3 = (const float*)d_in[9];
    const float* b3 = (const float*)d_in[10];
    const float* w4 = (const float*)d_in[11];
    const float* b4 = (const float*)d_in[12];
    const float* wz = (const float*)d_in[13];
    const float* bz = (const float*)d_in[14];
    const float* logs = (const float*)d_in[15];
    float* outp = (float*)d_out;
    unsigned int* wsp = (unsigned int*)d_ws;

    prep_kernel<<<58, 64, 0, stream>>>(w0, w1, w2, w3, w4, wz, wsp);
    init_logdet_kernel<<<1, 64, 0, stream>>>(logdet, outp);
    fused_kernel<<<dim3(16, 16, 16), 256, 0, stream>>>(
        input, ft, b0, b1, b2, b3, b4, bz, logs, wsp, outp);
}

// Round 4
// 234.300 us; speedup vs baseline: 9.7581x; 1.1536x over previous
//
#include <hip/hip_runtime.h>
#include <math.h>

// Problem constants
#define OUT_TAIL (16*8*256*256)   // logdet lives after the output tensor
#define HSTR   68                 // bf16 elems per H row (64 + 4 pad) -> odd dword-pair stride, b64 conflict-free
#define HROWB  136                // bytes per H row
#define SSTRIDE 2176              // 16 rows * HROWB = strip stride in bytes
#define INSTR  408                // in_s per-channel stride (shorts)

typedef __bf16 bf8_t __attribute__((ext_vector_type(8)));
typedef float  f4_t  __attribute__((ext_vector_type(4)));

__device__ __forceinline__ unsigned rne16u_(float x) {
    unsigned u = __float_as_uint(x);
    return (u + 0x7fffu + ((u >> 16) & 1u)) >> 16;
}
#if __has_builtin(__builtin_amdgcn_cvt_pk_bf16_f32)
__device__ __forceinline__ unsigned pack2f(float a, float b) {
    typedef __bf16 bf2_t __attribute__((ext_vector_type(2)));
    bf2_t r = __builtin_amdgcn_cvt_pk_bf16_f32(a, b);
    return __builtin_bit_cast(unsigned, r);
}
#else
__device__ __forceinline__ unsigned pack2f(float a, float b) {
    unsigned r;
    asm("v_cvt_pk_bf16_f32 %0, %1, %2" : "=v"(r) : "v"(a), "v"(b));
    return r;
}
#endif
__device__ __forceinline__ bf8_t as_bf8(uint4 u) { return __builtin_bit_cast(bf8_t, u); }

// ---------------- prep: split weights into hi/lo bf16 MFMA A-fragments ----------------
// frag ids: conv0: 0..7 (Mt*2+ks) ; layers1-4: 8+l*8+Mt*2+ks ; convz: 40+tap*2+ks
// record: [frag][lane][hi u32 x4 | lo u32 x4]
__global__ void prep_kernel(const float* __restrict__ w0, const float* __restrict__ w1,
                            const float* __restrict__ w2, const float* __restrict__ w3,
                            const float* __restrict__ w4, const float* __restrict__ wz,
                            unsigned int* __restrict__ ws) {
    int f = blockIdx.x;          // 0..57
    int lane = threadIdx.x;      // 0..63
    int m = lane & 15, qd = lane >> 4;
    float vals[8];
    if (f < 8) {                 // conv0: K = ch*9+tap, 54 real
        int Mt = f >> 1, ks = f & 1;
        int c = Mt * 16 + m;
        for (int j = 0; j < 8; ++j) {
            int k = ks * 32 + qd * 8 + j;
            vals[j] = (k < 54) ? w0[c * 54 + k] : 0.0f;
        }
    } else if (f < 40) {         // 1x1 layers
        int r = f - 8, l = r >> 3, fr = r & 7;
        int Mt = fr >> 1, ks = fr & 1;
        const float* wp = (l == 0) ? w1 : (l == 1) ? w2 : (l == 2) ? w3 : w4;
        int c = Mt * 16 + m;
        for (int j = 0; j < 8; ++j) vals[j] = wp[c * 64 + ks * 32 + qd * 8 + j];
    } else {                     // convz: per-tap
        int r = f - 40, tap = r >> 1, ks = r & 1;
        for (int j = 0; j < 8; ++j) {
            int k = ks * 32 + qd * 8 + j;
            vals[j] = wz[(m * 64 + k) * 9 + tap];
        }
    }
    unsigned int hi[4], lo[4];
    for (int i = 0; i < 4; ++i) {
        float a = vals[2 * i], c = vals[2 * i + 1];
        unsigned ha = rne16u_(a), hc = rne16u_(c);
        float ra = a - __uint_as_float(ha << 16);
        float rc = c - __uint_as_float(hc << 16);
        hi[i] = ha | (hc << 16);
        lo[i] = rne16u_(ra) | (rne16u_(rc) << 16);
    }
    unsigned int* p = ws + (size_t)(f * 64 + lane) * 8;
    for (int i = 0; i < 4; ++i) { p[i] = hi[i]; p[4 + i] = lo[i]; }
}

__global__ void init_logdet_kernel(const float* __restrict__ logdet, float* __restrict__ outp) {
    int i = threadIdx.x;
    if (i < 16) outp[OUT_TAIL + i] = logdet[i];
}

// ---------------- fused main kernel ----------------
// One block = one (batch, 16x16 tile). 256 threads = 4 waves.
// Wave w owns contiguous pixel strips: w0 pixels 0..95 (6 strips), w1 96..175, w2 176..255, w3 256..335.
// LDS: Hs[336][68] bf16 (45696 B) + in_s[2464] bf16 (4928 B) + red -> ~50.6 KB -> 3 blocks/CU
__global__ __launch_bounds__(256, 3)
void fused_kernel(const float* __restrict__ input, const float* __restrict__ ft,
                  const float* __restrict__ b0, const float* __restrict__ b1,
                  const float* __restrict__ b2, const float* __restrict__ b3,
                  const float* __restrict__ b4, const float* __restrict__ bz,
                  const float* __restrict__ logs, const unsigned int* __restrict__ wsp,
                  float* __restrict__ outp)
{
    __shared__ __align__(16) unsigned short Hs[336 * HSTR];
    __shared__ __align__(16) unsigned short in_s[2464];
    __shared__ float red[4];

    const int tid = threadIdx.x;
    const int bx = blockIdx.x, by = blockIdx.y, b = blockIdx.z;
    const int lane = tid & 63;
    const int ws_ = __builtin_amdgcn_readfirstlane(tid >> 6);   // wave id, scalar
    const int m = lane & 15, q = lane >> 4;
    const uint4* W4 = (const uint4*)wsp;
    const bool border = (bx == 0) | (bx == 15) | (by == 0) | (by == 15);

    // ---------------- stage input tile (bf16) + z1 fp32 passthrough ----------------
    {
        const int x0 = bx * 16 - 2, y0 = by * 16 - 2;
        int yy1 = tid / 20, xx1 = tid - yy1 * 20;
        int t2 = tid + 256;
        int yy2 = t2 / 20, xx2 = t2 - yy2 * 20;
        int gy1 = y0 + yy1, gx1 = x0 + xx1;
        int gy2 = y0 + yy2, gx2 = x0 + xx2;
        bool ok1 = ((unsigned)gy1 < 256u) && ((unsigned)gx1 < 256u);
        bool ok2 = ((unsigned)gy2 < 256u) && ((unsigned)gx2 < 256u);
        #pragma unroll
        for (int c = 0; c < 6; ++c) {
            const float* src = (c < 4) ? input + (size_t)(b * 8 + c) * 65536
                                       : ft + (size_t)(b * 2 + (c - 4)) * 65536;
            float v1 = ok1 ? src[gy1 * 256 + gx1] : 0.0f;
            in_s[c * INSTR + yy1 * 20 + xx1] = (unsigned short)(pack2f(v1, 0.0f) & 0xffffu);
            if (tid < 144) {
                float v2 = ok2 ? src[gy2 * 256 + gx2] : 0.0f;
                in_s[c * INSTR + yy2 * 20 + xx2] = (unsigned short)(pack2f(v2, 0.0f) & 0xffffu);
            }
        }
        // z1 exact fp32 passthrough: 4 floats per thread
        int c = tid >> 6;
        int rem = (tid & 63) * 4;
        int oy = rem >> 4, ox = rem & 15;
        size_t o = ((size_t)(b * 8 + c) * 256 + by * 16 + oy) * 256 + bx * 16 + ox;
        *(float4*)&outp[o] = *(const float4*)&input[o];
    }
    __syncthreads();

    const int nstrip = (ws_ == 0) ? 6 : 5;
    const int pbase  = (ws_ == 0) ? 0 : (80 * ws_ + 16);
    const int pix0   = pbase + m;
    const int A0 = pix0 * HROWB + q * 16;   // H B-read base (bytes)
    const int W0 = pix0 * HROWB + q * 8;    // H write base (bytes); + s*SSTRIDE + Mt*32

    // ---------------- conv0 3x3 (6->64) via MFMA (hi-only), im2col gather from in_s ----------------
    {
        int koffB[16];                      // byte offsets into in_s, per-lane (q-dependent)
        #pragma unroll
        for (int ks = 0; ks < 2; ++ks)
            #pragma unroll
            for (int j = 0; j < 8; ++j) {
                int k = ks * 32 + q * 8 + j;
                int ch = k / 9, tap = k - ch * 9;
                int ky = tap / 3, kx = tap - ky * 3;
                koffB[ks * 8 + j] = (k < 54) ? (ch * INSTR + ky * 20 + kx) * 2 : 0;
            }
        uint4 Ah[8];
        #pragma unroll
        for (int f = 0; f < 8; ++f)
            Ah[f] = W4[((size_t)(f * 64) + lane) * 2];
        f4_t bv4[4];
        #pragma unroll
        for (int Mt = 0; Mt < 4; ++Mt)
            #pragma unroll
            for (int r = 0; r < 4; ++r) bv4[Mt][r] = b0[Mt * 16 + q * 4 + r];

        int cpy = (pix0 * 1821) >> 15;      // pix0 / 18 (exact for 0..335)
        int cpx = pix0 - cpy * 18;
        #pragma unroll
        for (int s = 0; s < 6; ++s) {
            if (s < nstrip) {
                int ib = (cpy * 20 + cpx) * 2;
                unsigned e[16];
                #pragma unroll
                for (int i = 0; i < 16; ++i)
                    e[i] = *(const unsigned short*)((const char*)in_s + ib + koffB[i]);
                uint4 B0 = make_uint4(e[0] | (e[1] << 16), e[2] | (e[3] << 16),
                                      e[4] | (e[5] << 16), e[6] | (e[7] << 16));
                uint4 B1 = make_uint4(e[8] | (e[9] << 16), e[10] | (e[11] << 16),
                                      e[12] | (e[13] << 16), e[14] | (e[15] << 16));
                #pragma unroll
                for (int Mt = 0; Mt < 4; ++Mt) {
                    f4_t a = __builtin_amdgcn_mfma_f32_16x16x32_bf16(as_bf8(Ah[Mt*2+0]), as_bf8(B0), bv4[Mt], 0, 0, 0);
                    a = __builtin_amdgcn_mfma_f32_16x16x32_bf16(as_bf8(Ah[Mt*2+1]), as_bf8(B1), a, 0, 0, 0);
                    uint2 pr;
                    pr.x = pack2f(fmaxf(a[0], 0.f), fmaxf(a[1], 0.f));
                    pr.y = pack2f(fmaxf(a[2], 0.f), fmaxf(a[3], 0.f));
                    *(uint2*)((char*)Hs + W0 + s * SSTRIDE + Mt * 32) = pr;
                }
            }
            cpx += 16;
            if (cpx >= 18) { cpx -= 18; cpy += 1; }
        }
    }

    // ---------------- 4x (1x1 conv 64->64 + ReLU) via MFMA (hi-only), in-place H, no barriers ----------------
    #pragma unroll 1
    for (int l = 0; l < 4; ++l) {
        const float* bl = (l == 0) ? b1 : (l == 1) ? b2 : (l == 2) ? b3 : b4;
        uint4 Ah[8];
        #pragma unroll
        for (int f = 0; f < 8; ++f)
            Ah[f] = W4[((size_t)((8 + l * 8 + f) * 64) + lane) * 2];
        f4_t bv4[4];
        #pragma unroll
        for (int Mt = 0; Mt < 4; ++Mt)
            #pragma unroll
            for (int r = 0; r < 4; ++r) bv4[Mt][r] = bl[Mt * 16 + q * 4 + r];

        #pragma unroll
        for (int s = 0; s < 6; ++s) {
            if (s < nstrip) {
                const char* rp = (const char*)Hs + A0 + s * SSTRIDE;
                uint2 a0 = *(const uint2*)(rp);
                uint2 a1 = *(const uint2*)(rp + 8);
                uint2 a2 = *(const uint2*)(rp + 64);
                uint2 a3 = *(const uint2*)(rp + 72);
                uint4 B0 = make_uint4(a0.x, a0.y, a1.x, a1.y);
                uint4 B1 = make_uint4(a2.x, a2.y, a3.x, a3.y);
                #pragma unroll
                for (int Mt = 0; Mt < 4; ++Mt) {
                    f4_t a = __builtin_amdgcn_mfma_f32_16x16x32_bf16(as_bf8(Ah[Mt*2+0]), as_bf8(B0), bv4[Mt], 0, 0, 0);
                    a = __builtin_amdgcn_mfma_f32_16x16x32_bf16(as_bf8(Ah[Mt*2+1]), as_bf8(B1), a, 0, 0, 0);
                    uint2 pr;
                    pr.x = pack2f(fmaxf(a[0], 0.f), fmaxf(a[1], 0.f));
                    pr.y = pack2f(fmaxf(a[2], 0.f), fmaxf(a[3], 0.f));
                    *(uint2*)((char*)Hs + W0 + s * SSTRIDE + Mt * 32) = pr;
                }
            }
        }
    }

    // ---------------- border blocks: zero H rows outside the image (convz zero-pad) ----------------
    if (border) {
        #pragma unroll
        for (int s = 0; s < 6; ++s) {
            if (s < nstrip) {
                int pixs = pix0 + 16 * s;
                int pys = (pixs * 1821) >> 15;
                int pxs = pixs - pys * 18;
                int gy = by * 16 - 1 + pys, gx = bx * 16 - 1 + pxs;
                if (!(((unsigned)gy < 256u) && ((unsigned)gx < 256u))) {
                    char* zp = (char*)Hs + A0 + s * SSTRIDE;   // q-chunks cover all 64 ch
                    *(uint2*)(zp)      = make_uint2(0, 0);
                    *(uint2*)(zp + 8)  = make_uint2(0, 0);
                    *(uint2*)(zp + 64) = make_uint2(0, 0);
                    *(uint2*)(zp + 72) = make_uint2(0, 0);
                }
            }
        }
    }
    __syncthreads();

    // ---------------- convz 3x3 (64->16) via MFMA (hi+lo) + RQ spline (shuffle-free epilogue) ----------------
    {
        // prefetch spline inputs x (z2 channels) and per-channel constants
        float xv[4];
        #pragma unroll
        for (int rr = 0; rr < 4; ++rr) {
            int gy = by * 16 + ws_ * 4 + rr;
            xv[rr] = input[((size_t)(b * 8 + 4 + q) * 256 + gy) * 256 + bx * 16 + m];
        }
        float bzv[4], scl[4];
        #pragma unroll
        for (int r = 0; r < 4; ++r) {
            int c = q * 4 + r;
            bzv[r] = bz[c];
            scl[r] = __expf(3.0f * logs[c]);
        }
        f4_t acc[4];
        #pragma unroll
        for (int rr = 0; rr < 4; ++rr) { acc[rr][0]=0.f; acc[rr][1]=0.f; acc[rr][2]=0.f; acc[rr][3]=0.f; }
        const int Z0 = (ws_ * 72 + m) * HROWB + q * 16;
        #pragma unroll
        for (int tap = 0; tap < 9; ++tap) {
            const int ky = tap / 3, kx = tap - ky * 3;
            #pragma unroll
            for (int ks = 0; ks < 2; ++ks) {
                const uint4* p = W4 + ((size_t)((40 + tap * 2 + ks) * 64) + lane) * 2;
                uint4 ah = p[0], al = p[1];
                #pragma unroll
                for (int rr = 0; rr < 4; ++rr) {
                    const char* zp = (const char*)Hs + Z0 + ((rr + ky) * 18 + kx) * HROWB + ks * 64;
                    uint2 u0 = *(const uint2*)zp;
                    uint2 u1 = *(const uint2*)(zp + 8);
                    uint4 Bv = make_uint4(u0.x, u0.y, u1.x, u1.y);
                    acc[rr] = __builtin_amdgcn_mfma_f32_16x16x32_bf16(as_bf8(ah), as_bf8(Bv), acc[rr], 0, 0, 0);
                    acc[rr] = __builtin_amdgcn_mfma_f32_16x16x32_bf16(as_bf8(al), as_bf8(Bv), acc[rr], 0, 0, 0);
                }
            }
        }
        // spline: lane(m,q) holds params w,h,d,shift for channel co=q at pixel (oy, ox=m) in regs 0..3
        float lad_sum = 0.0f;
        #pragma unroll
        for (int rr = 0; rr < 4; ++rr) {
            int gy = by * 16 + ws_ * 4 + rr, gx = bx * 16 + m;
            size_t xi = ((size_t)(b * 8 + 4 + q) * 256 + gy) * 256 + gx;
            float x = xv[rr];
            float pw = (acc[rr][0] + bzv[0]) * scl[0];
            float ph = (acc[rr][1] + bzv[1]) * scl[1];
            float pd = (acc[rr][2] + bzv[2]) * scl[2];
            float ps = (acc[rr][3] + bzv[3]) * scl[3];

            bool inside = (x > -0.5f) && (x < 0.5f);
            float xs = inside ? x : 0.0f;
            float wf = 1.0f / (1.0f + __expf(-pw)) * 0.998f + 0.001f;
            float hh = 1.0f / (1.0f + __expf(-ph)) * 0.998f + 0.001f;
            float dd = __expf(pd) * 0.999f + 0.001f;
            bool bin1 = (xs >= wf - 0.5f);
            float in_cw = bin1 ? (wf - 0.5f) : -0.5f;
            float in_w  = bin1 ? (1.0f - wf) : wf;
            float in_ch = bin1 ? (hh - 0.5f) : -0.5f;
            float in_h  = bin1 ? (1.0f - hh) : hh;
            float delta = in_h / in_w;
            float d0 = bin1 ? dd : 1.0f;
            float d1 = bin1 ? 1.0f : dd;
            float theta = (xs - in_cw) / in_w;
            float t1mt  = theta * (1.0f - theta);
            float denom = delta + (d0 + d1 - 2.0f * delta) * t1mt;
            float th2   = theta * theta;
            float ov    = in_ch + in_h * (delta * th2 + d0 * t1mt) / denom;
            float omt   = 1.0f - theta;
            float dnum  = delta * delta * (d1 * th2 + 2.0f * delta * t1mt + d0 * omt * omt);
            float lad   = __logf(dnum) - 2.0f * __logf(denom);
            ov  = fminf(fmaxf(ov, -0.5f), 0.5f);
            ov  = inside ? ov : x;
            lad = inside ? lad : 0.0f;
            outp[xi] = ov + ps;
            lad_sum += lad;
        }
        #pragma unroll
        for (int off = 32; off > 0; off >>= 1)
            lad_sum += __shfl_down(lad_sum, off, 64);
        if (lane == 0) red[ws_] = lad_sum;
    }
    __syncthreads();
    if (tid == 0)
        atomicAdd(&outp[OUT_TAIL + b], red[0] + red[1] + red[2] + red[3]);
}

extern "C" void kernel_launch(void* const* d_in, const int* in_sizes, int n_in,
                              void* d_out, int out_size, void* d_ws, size_t ws_size,
                              hipStream_t stream) {
    const float* input  = (const float*)d_in[0];
    const float* logdet = (const float*)d_in[1];
    const float* ft     = (const float*)d_in[2];
    const float* w0 = (const float*)d_in[3];
    const float* b0 = (const float*)d_in[4];
    const float* w1 = (const float*)d_in[5];
    const float* b1 = (const float*)d_in[6];
    const float* w2 = (const float*)d_in[7];
    const float* b2 = (const float*)d_in[8];
    const float* w3 = (const float*)d_in[9];
    const float* b3 = (const float*)d_in[10];
    const float* w4 = (const float*)d_in[11];
    const float* b4 = (const float*)d_in[12];
    const float* wz = (const float*)d_in[13];
    const float* bz = (const float*)d_in[14];
    const float* logs = (const float*)d_in[15];
    float* outp = (float*)d_out;
    unsigned int* wsp = (unsigned int*)d_ws;

    prep_kernel<<<58, 64, 0, stream>>>(w0, w1, w2, w3, w4, wz, wsp);
    init_logdet_kernel<<<1, 64, 0, stream>>>(logdet, outp);
    fused_kernel<<<dim3(16, 16, 16), 256, 0, stream>>>(
        input, ft, b0, b1, b2, b3, b4, bz, logs, wsp, outp);
}